// Round 1
// baseline (1367.342 us; speedup 1.0000x reference)
//
#include <hip/hip_runtime.h>
#include <math.h>

// ---------------- problem constants ----------------
#define E_DIM 1024
#define D_DIM 256
#define N_PATCH 60000
#define BIN 20000          // N / K
#define TP 16              // patches per tile
#define NB 512             // blocks in main kernel
#define TOTAL_TILES 3750   // N / TP
#define NHQ 24             // heads(8) * queries(3)
#define LN_EPS 1e-5f

// ---------------- workspace layout (float offsets) ----------------
#define WS_BAG 0                        // 6*256
#define WS_SEL 1536                     // 3*256
#define WS_GENE 2304                    // 256
#define WS_QV 2560                      // 3*256  (pre-scaled by 1/sqrt(32))
#define WS_PM 3584                      // NB*24
#define WS_PL (WS_PM + NB*NHQ)          // NB*24
#define WS_PACC (WS_PL + NB*NHQ)        // NB*768
#define WS_PPOOL (WS_PACC + NB*768)     // NB*768
#define WS_ATTN (WS_PPOOL + NB*768)     // 768
#define WS_POOLED (WS_ATTN + 768)       // 768
// total ~816k floats ~ 3.3 MB

struct PrepArgs {
    const float* xo[6];
    const float* w1[6];
    int sz[6];
};

// ---------------- per-pathway SNN: elu(elu(x@w1+b1)@w2+b2) ----------------
__global__ void snn_kernel(PrepArgs pa, const float* __restrict__ sb1,
                           const float* __restrict__ sw2, const float* __restrict__ sb2,
                           float* __restrict__ bag) {
    __shared__ float xsh[600];
    __shared__ float t1sh[256];
    const int i = blockIdx.x;
    const int t = threadIdx.x;
    const int s = pa.sz[i];
    const float* xo = pa.xo[i];
    const float* w1 = pa.w1[i];
    for (int j = t; j < s; j += 256) xsh[j] = xo[j];
    __syncthreads();
    float acc = sb1[i * 256 + t];
    for (int j = 0; j < s; ++j) acc += xsh[j] * w1[j * 256 + t];
    t1sh[t] = acc > 0.f ? acc : expm1f(acc);
    __syncthreads();
    float acc2 = sb2[i * 256 + t];
    const float* w2 = sw2 + (size_t)i * 256 * 256;
    for (int j = 0; j < 256; ++j) acc2 += t1sh[j] * w2[j * 256 + t];
    bag[i * 256 + t] = acc2 > 0.f ? acc2 : expm1f(acc2);
}

// ---------------- gene attention scores, top-3 select, q projection ----------------
__global__ void select_kernel(const float* __restrict__ wa1, const float* __restrict__ ba1,
                              const float* __restrict__ wa2, const float* __restrict__ ba2,
                              const float* __restrict__ wq, const float* __restrict__ bq,
                              float* __restrict__ wsf) {
    __shared__ float bsh[6][256];
    __shared__ float ysh[64];
    __shared__ float ssh[8];
    __shared__ int isel[3];
    const int t = threadIdx.x;
    for (int j = t; j < 1536; j += 256) ((float*)bsh)[j] = wsf[WS_BAG + j];
    __syncthreads();
    // scores per pathway: relu(bag@wa1+ba1)@wa2+ba2
    for (int i = 0; i < 6; ++i) {
        if (t < 64) {
            float acc = ba1[t];
            for (int j = 0; j < 256; ++j) acc += bsh[i][j] * wa1[j * 64 + t];
            ysh[t] = fmaxf(acc, 0.f) * wa2[t];
        }
        __syncthreads();
        if (t == 0) {
            float sc = ba2[0];
            for (int j = 0; j < 64; ++j) sc += ysh[j];
            ssh[i] = sc;
        }
        __syncthreads();
    }
    // top-3 by score (softmax is monotonic; ties -> smaller index, matches lax.top_k)
    if (t == 0) {
        float sc[6];
        for (int i = 0; i < 6; ++i) sc[i] = ssh[i];
        for (int k = 0; k < 3; ++k) {
            int best = 0; float bv = sc[0];
            for (int i = 1; i < 6; ++i) if (sc[i] > bv) { bv = sc[i]; best = i; }
            isel[k] = best;
            sc[best] = -INFINITY;
        }
    }
    __syncthreads();
    float g = 0.f;
    for (int k = 0; k < 3; ++k) {
        float v = bsh[isel[k]][t];
        wsf[WS_SEL + k * 256 + t] = v;
        g += v;
    }
    wsf[WS_GENE + t] = g * (1.f / 3.f);
    // q = (selected @ wq + bq) * rsqrt(32)
    for (int k = 0; k < 3; ++k) {
        float acc = bq[t];
        const float* srow = bsh[isel[k]];
        for (int j = 0; j < 256; ++j) acc += srow[j] * wq[j * 256 + t];
        wsf[WS_QV + k * 256 + t] = acc * 0.17677669529663687f;
    }
}

// ---------------- fused main: wsi proj + k/v proj + flash attention partials + pooling ----------------
__global__ __launch_bounds__(256, 2) void main_kernel(
    const float* __restrict__ xp, const float* __restrict__ wp, const float* __restrict__ bp,
    const float* __restrict__ wk, const float* __restrict__ bk,
    const float* __restrict__ wv, const float* __restrict__ bv,
    float* __restrict__ wsf)
{
    __shared__ float x_lds[TP][128];
    __shared__ float wsi_lds[TP][256];
    __shared__ float k_lds[TP][260];   // +4 pad: breaks 32-way bank conflict in score phase
    __shared__ float v_lds[TP][256];
    __shared__ float q_lds[NHQ][32];
    __shared__ float s_lds[NHQ][TP];
    __shared__ float p_lds[NHQ][TP];
    __shared__ float m_sh[NHQ];
    __shared__ float l_sh[NHQ];
    __shared__ float corr_sh[NHQ];

    const int tid = threadIdx.x;
    const int b = blockIdx.x;
    const int dg = tid & 63;
    const int pg = tid >> 6;
    const int d0 = dg * 4;
    const int p0 = pg * 4;

    for (int j = tid; j < 768; j += 256) {
        int kq = j >> 8, r = j & 255, h = r >> 5, dd = r & 31;
        q_lds[h * 3 + kq][dd] = wsf[WS_QV + j];
    }
    if (tid < NHQ) { m_sh[tid] = -INFINITY; l_sh[tid] = 0.f; }

    float a_acc[3] = {0.f, 0.f, 0.f};
    float pool_acc[3] = {0.f, 0.f, 0.f};
    const float4 bp4 = *(const float4*)(bp + d0);
    const float4 bk4 = *(const float4*)(bk + d0);
    const float4 bv4 = *(const float4*)(bv + d0);
    __syncthreads();

    for (int tt = b; tt < TOTAL_TILES; tt += NB) {
        const int n0 = tt * TP;
        // ---- phase 1: wsi = relu(x @ wp + bp), 16 patches x 256 dims ----
        float facc[16];
#pragma unroll
        for (int i = 0; i < 16; ++i) facc[i] = 0.f;

        for (int kb = 0; kb < E_DIM; kb += 128) {
            __syncthreads();
#pragma unroll
            for (int j = 0; j < 2; ++j) {
                int idx = tid + j * 256;
                int p = idx >> 5, c = idx & 31;
                *(float4*)&x_lds[p][c * 4] =
                    *(const float4*)(xp + (size_t)(n0 + p) * E_DIM + kb + c * 4);
            }
            __syncthreads();
#pragma unroll 2
            for (int kk = 0; kk < 128; kk += 4) {
                float xv[4][4];
#pragma unroll
                for (int p = 0; p < 4; ++p) {
                    float4 t4 = *(float4*)&x_lds[p0 + p][kk];
                    xv[p][0] = t4.x; xv[p][1] = t4.y; xv[p][2] = t4.z; xv[p][3] = t4.w;
                }
#pragma unroll
                for (int kkj = 0; kkj < 4; ++kkj) {
                    float4 w = *(const float4*)(wp + (size_t)(kb + kk + kkj) * 256 + d0);
#pragma unroll
                    for (int p = 0; p < 4; ++p) {
                        facc[p * 4 + 0] += xv[p][kkj] * w.x;
                        facc[p * 4 + 1] += xv[p][kkj] * w.y;
                        facc[p * 4 + 2] += xv[p][kkj] * w.z;
                        facc[p * 4 + 3] += xv[p][kkj] * w.w;
                    }
                }
            }
        }
#pragma unroll
        for (int p = 0; p < 4; ++p) {
            float4 r;
            r.x = fmaxf(facc[p * 4 + 0] + bp4.x, 0.f);
            r.y = fmaxf(facc[p * 4 + 1] + bp4.y, 0.f);
            r.z = fmaxf(facc[p * 4 + 2] + bp4.z, 0.f);
            r.w = fmaxf(facc[p * 4 + 3] + bp4.w, 0.f);
            *(float4*)&wsi_lds[p0 + p][d0] = r;
        }
        __syncthreads();

        // ---- pooling partials (thread owns dim tid) ----
#pragma unroll
        for (int p = 0; p < TP; ++p) {
            float v = wsi_lds[p][tid];
            int bin = (n0 + p) / BIN;
            pool_acc[0] += (bin == 0) ? v : 0.f;
            pool_acc[1] += (bin == 1) ? v : 0.f;
            pool_acc[2] += (bin == 2) ? v : 0.f;
        }

        // ---- phase 2: k = wsi@wk+bk, v = wsi@wv+bv ----
        float kacc[16], vacc[16];
#pragma unroll
        for (int i = 0; i < 16; ++i) { kacc[i] = 0.f; vacc[i] = 0.f; }
#pragma unroll 2
        for (int kk = 0; kk < 256; kk += 4) {
            float xv[4][4];
#pragma unroll
            for (int p = 0; p < 4; ++p) {
                float4 t4 = *(float4*)&wsi_lds[p0 + p][kk];
                xv[p][0] = t4.x; xv[p][1] = t4.y; xv[p][2] = t4.z; xv[p][3] = t4.w;
            }
#pragma unroll
            for (int kkj = 0; kkj < 4; ++kkj) {
                float4 wk4 = *(const float4*)(wk + (size_t)(kk + kkj) * 256 + d0);
                float4 wv4 = *(const float4*)(wv + (size_t)(kk + kkj) * 256 + d0);
#pragma unroll
                for (int p = 0; p < 4; ++p) {
                    kacc[p * 4 + 0] += xv[p][kkj] * wk4.x;
                    kacc[p * 4 + 1] += xv[p][kkj] * wk4.y;
                    kacc[p * 4 + 2] += xv[p][kkj] * wk4.z;
                    kacc[p * 4 + 3] += xv[p][kkj] * wk4.w;
                    vacc[p * 4 + 0] += xv[p][kkj] * wv4.x;
                    vacc[p * 4 + 1] += xv[p][kkj] * wv4.y;
                    vacc[p * 4 + 2] += xv[p][kkj] * wv4.z;
                    vacc[p * 4 + 3] += xv[p][kkj] * wv4.w;
                }
            }
        }
#pragma unroll
        for (int p = 0; p < 4; ++p) {
            float4 rk;
            rk.x = kacc[p * 4 + 0] + bk4.x; rk.y = kacc[p * 4 + 1] + bk4.y;
            rk.z = kacc[p * 4 + 2] + bk4.z; rk.w = kacc[p * 4 + 3] + bk4.w;
            *(float4*)&k_lds[p0 + p][d0] = rk;
            float4 rv;
            rv.x = vacc[p * 4 + 0] + bv4.x; rv.y = vacc[p * 4 + 1] + bv4.y;
            rv.z = vacc[p * 4 + 2] + bv4.z; rv.w = vacc[p * 4 + 3] + bv4.w;
            *(float4*)&v_lds[p0 + p][d0] = rv;
        }
        __syncthreads();

        // ---- phase 3: scores s[hq][p] = q_hq . k_p(head)  (q pre-scaled) ----
        for (int e = tid; e < NHQ * TP; e += 256) {
            int hq = e >> 4, p = e & 15, h = hq / 3;
            const float* kr = &k_lds[p][h * 32];
            const float* qr = q_lds[hq];
            float s = 0.f;
#pragma unroll
            for (int dd = 0; dd < 32; ++dd) s += qr[dd] * kr[dd];
            s_lds[hq][p] = s;
        }
        __syncthreads();

        // ---- phase 4: online softmax state ----
        if (tid < NHQ) {
            const int hq = tid;
            float m_old = m_sh[hq];
            float tmax = -INFINITY;
#pragma unroll
            for (int p = 0; p < TP; ++p) tmax = fmaxf(tmax, s_lds[hq][p]);
            float mnew = fmaxf(m_old, tmax);
            float corr = expf(m_old - mnew);
            float l = l_sh[hq] * corr;
#pragma unroll
            for (int p = 0; p < TP; ++p) {
                float e = expf(s_lds[hq][p] - mnew);
                p_lds[hq][p] = e;
                l += e;
            }
            m_sh[hq] = mnew; l_sh[hq] = l; corr_sh[hq] = corr;
        }
        __syncthreads();

        // ---- phase 5: PV accumulate (thread owns 3 of 24x32 outputs) ----
#pragma unroll
        for (int j = 0; j < 3; ++j) {
            int e = tid + j * 256;
            int hq = e >> 5, dd = e & 31, h = hq / 3;
            float acc = a_acc[j] * corr_sh[hq];
#pragma unroll
            for (int p = 0; p < TP; ++p) acc += p_lds[hq][p] * v_lds[p][h * 32 + dd];
            a_acc[j] = acc;
        }
        __syncthreads();
    }

    // ---- write per-block partials ----
    if (tid < NHQ) {
        wsf[WS_PM + b * NHQ + tid] = m_sh[tid];
        wsf[WS_PL + b * NHQ + tid] = l_sh[tid];
    }
#pragma unroll
    for (int j = 0; j < 3; ++j)
        wsf[WS_PACC + b * 768 + tid + j * 256] = a_acc[j];
#pragma unroll
    for (int bin = 0; bin < 3; ++bin)
        wsf[WS_PPOOL + b * 768 + bin * 256 + tid] = pool_acc[bin];
}

// ---------------- combine partials: attention (24 blocks) + pooling (3 blocks) ----------------
__global__ void combine_kernel(float* __restrict__ wsf) {
    const int bidx = blockIdx.x;
    const int t = threadIdx.x;
    if (bidx < NHQ) {
        const int hq = bidx;
        float lm = -INFINITY;
        for (int b = t; b < NB; b += 64) lm = fmaxf(lm, wsf[WS_PM + b * NHQ + hq]);
#pragma unroll
        for (int o = 32; o > 0; o >>= 1) lm = fmaxf(lm, __shfl_xor(lm, o));
        const float M = lm;
        float L = 0.f;
        for (int b = t; b < NB; b += 64)
            L += wsf[WS_PL + b * NHQ + hq] * expf(wsf[WS_PM + b * NHQ + hq] - M);
#pragma unroll
        for (int o = 32; o > 0; o >>= 1) L += __shfl_xor(L, o);
        const int dd = t & 31, half = t >> 5;
        float O = 0.f;
        for (int b = half; b < NB; b += 2)
            O += wsf[WS_PACC + b * 768 + hq * 32 + dd] * expf(wsf[WS_PM + b * NHQ + hq] - M);
        O += __shfl_xor(O, 32);
        if (t < 32) {
            int h = hq / 3, kq = hq - h * 3;
            wsf[WS_ATTN + kq * 256 + h * 32 + dd] = O / L;
        }
    } else {
        const int bin = bidx - NHQ;
        for (int rep = 0; rep < 4; ++rep) {
            int d = rep * 64 + t;
            float s = 0.f;
            for (int b = 0; b < NB; ++b) s += wsf[WS_PPOOL + b * 768 + bin * 256 + d];
            wsf[WS_POOLED + bin * 256 + d] = s * (1.f / BIN);
        }
    }
}

// ---------------- epilogue: wo proj, LN1, fusion MLP, LN2, classifier ----------------
__device__ __forceinline__ float block_sum256(float v, float* red, int t) {
#pragma unroll
    for (int o = 32; o > 0; o >>= 1) v += __shfl_xor(v, o);
    if ((t & 63) == 0) red[t >> 6] = v;
    __syncthreads();
    float r = red[0] + red[1] + red[2] + red[3];
    __syncthreads();
    return r;
}

__global__ void final_kernel(const float* __restrict__ wo, const float* __restrict__ bo,
                             const float* __restrict__ ln1g, const float* __restrict__ ln1b,
                             const float* __restrict__ wf1, const float* __restrict__ bf1,
                             const float* __restrict__ wf2, const float* __restrict__ bf2,
                             const float* __restrict__ ln2g, const float* __restrict__ ln2b,
                             const float* __restrict__ wc, const float* __restrict__ bc,
                             float* __restrict__ wsf, float* __restrict__ out) {
    __shared__ float attnC[3][256];
    __shared__ float att[3][256];
    __shared__ float amean[256];
    __shared__ float gf[256];
    __shared__ float f1[256];
    __shared__ float red[256];
    const int t = threadIdx.x;
    for (int j = t; j < 768; j += 256) ((float*)attnC)[j] = wsf[WS_ATTN + j];
    gf[t] = wsf[WS_GENE + t];
    __syncthreads();
    // attn_out = attnC @ wo + bo; add pooled; LN1 per row
    for (int kq = 0; kq < 3; ++kq) {
        float acc = bo[t];
        for (int j = 0; j < 256; ++j) acc += attnC[kq][j] * wo[j * 256 + t];
        float x = acc + wsf[WS_POOLED + kq * 256 + t];
        float m = block_sum256(x, red, t) * (1.f / 256.f);
        float dv = x - m;
        float var = block_sum256(dv * dv, red, t) * (1.f / 256.f);
        att[kq][t] = dv * rsqrtf(var + LN_EPS) * ln1g[t] + ln1b[t];
    }
    __syncthreads();
    amean[t] = (att[0][t] + att[1][t] + att[2][t]) * (1.f / 3.f);
    __syncthreads();
    // f1 = relu([amean, gene] @ wf1 + bf1)
    {
        float acc = bf1[t];
        for (int j = 0; j < 256; ++j) acc += amean[j] * wf1[j * 256 + t];
        for (int j = 0; j < 256; ++j) acc += gf[j] * wf1[(256 + j) * 256 + t];
        f1[t] = fmaxf(acc, 0.f);
    }
    __syncthreads();
    // f2 = relu(f1 @ wf2 + bf2); fused = LN2(f2 + amean)
    float acc2 = bf2[t];
    for (int j = 0; j < 256; ++j) acc2 += f1[j] * wf2[j * 256 + t];
    float y = fmaxf(acc2, 0.f) + amean[t];
    float m2 = block_sum256(y, red, t) * (1.f / 256.f);
    float dv2 = y - m2;
    float v2 = block_sum256(dv2 * dv2, red, t) * (1.f / 256.f);
    float fused = dv2 * rsqrtf(v2 + LN_EPS) * ln2g[t] + ln2b[t];
    red[t] = fused;
    __syncthreads();
    if (t < 4) {
        float o = bc[t];
        for (int j = 0; j < 256; ++j) o += red[j] * wc[j * 4 + t];
        out[t] = o;
    }
}

// ---------------- launcher ----------------
extern "C" void kernel_launch(void* const* d_in, const int* in_sizes, int n_in,
                              void* d_out, int out_size, void* d_ws, size_t ws_size,
                              hipStream_t stream) {
    const float* xp = (const float*)d_in[0];
    PrepArgs pa;
    for (int i = 0; i < 6; ++i) {
        pa.xo[i] = (const float*)d_in[1 + i];
        pa.w1[i] = (const float*)d_in[7 + i];
        pa.sz[i] = in_sizes[1 + i];
    }
    const float* sb1 = (const float*)d_in[13];
    const float* sw2 = (const float*)d_in[14];
    const float* sb2 = (const float*)d_in[15];
    const float* wp  = (const float*)d_in[16];
    const float* bp  = (const float*)d_in[17];
    const float* wa1 = (const float*)d_in[18];
    const float* ba1 = (const float*)d_in[19];
    const float* wa2 = (const float*)d_in[20];
    const float* ba2 = (const float*)d_in[21];
    const float* wq  = (const float*)d_in[22];
    const float* wk  = (const float*)d_in[23];
    const float* wv  = (const float*)d_in[24];
    const float* wo  = (const float*)d_in[25];
    const float* bq  = (const float*)d_in[26];
    const float* bk  = (const float*)d_in[27];
    const float* bv  = (const float*)d_in[28];
    const float* bo  = (const float*)d_in[29];
    const float* ln1g = (const float*)d_in[30];
    const float* ln1b = (const float*)d_in[31];
    const float* wf1 = (const float*)d_in[32];
    const float* bf1 = (const float*)d_in[33];
    const float* wf2 = (const float*)d_in[34];
    const float* bf2 = (const float*)d_in[35];
    const float* ln2g = (const float*)d_in[36];
    const float* ln2b = (const float*)d_in[37];
    const float* wc  = (const float*)d_in[38];
    const float* bc  = (const float*)d_in[39];

    float* wsf = (float*)d_ws;
    float* out = (float*)d_out;

    snn_kernel<<<dim3(6), dim3(256), 0, stream>>>(pa, sb1, sw2, sb2, wsf + WS_BAG);
    select_kernel<<<dim3(1), dim3(256), 0, stream>>>(wa1, ba1, wa2, ba2, wq, bq, wsf);
    main_kernel<<<dim3(NB), dim3(256), 0, stream>>>(xp, wp, bp, wk, bk, wv, bv, wsf);
    combine_kernel<<<dim3(27), dim3(64), 0, stream>>>(wsf);
    final_kernel<<<dim3(1), dim3(256), 0, stream>>>(wo, bo, ln1g, ln1b, wf1, bf1, wf2, bf2,
                                                    ln2g, ln2b, wc, bc, wsf, out);
}

// Round 2
// 1223.890 us; speedup vs baseline: 1.1172x; 1.1172x over previous
//
#include <hip/hip_runtime.h>
#include <hip/hip_bf16.h>
#include <math.h>

typedef unsigned short ushort_t;
typedef __attribute__((ext_vector_type(8))) short bf16x8;
typedef __attribute__((ext_vector_type(4))) float f32x4;

// ---------------- problem constants ----------------
#define NB 512
#define TP 32
#define NTILES 1875        // 60000 / 32
#define NHQ 24             // 8 heads * 3 queries
#define LN_EPS 1e-5f

// ---------------- workspace layout (float offsets) ----------------
#define WS_BAG 0                        // 6*256
#define WS_SEL 1536                     // 3*256
#define WS_GENE 2304                    // 256
#define WS_QV 2560                      // 3*256 (pre-scaled by 1/sqrt(32))
#define WS_PM 3584                      // NB*24
#define WS_PL (WS_PM + NB*NHQ)
#define WS_PACC (WS_PL + NB*NHQ)        // NB*768
#define WS_PPOOL (WS_PACC + NB*768)     // NB*768
#define WS_ATTN (WS_PPOOL + NB*768)     // 768
#define WS_POOLED (WS_ATTN + 768)       // 768
#define WS_BF16 (WS_POOLED + 768)       // bf16 region (16B-aligned: offset*4 % 16 == 0)
// ushort offsets inside bf16 region
#define U_WPT 0                         // wpT [256][1024]
#define U_WKT 262144                    // wkT [256][256]
#define U_WVT (262144 + 65536)          // wvT [256][256]

// ---------------- helpers ----------------
__device__ __forceinline__ ushort_t f2bf(float f) {
    __hip_bfloat16 h = __float2bfloat16(f);
    return *reinterpret_cast<ushort_t*>(&h);
}
__device__ __forceinline__ float bf2f(unsigned int u) {
    union { unsigned int i; float f; } c; c.i = u << 16; return c.f;
}
__device__ __forceinline__ unsigned int pk2(float a, float b) {
    return (unsigned int)f2bf(a) | ((unsigned int)f2bf(b) << 16);
}

// ---------------- prep: transpose weights to bf16 k-contiguous ----------------
__global__ void prep_kernel(const float* __restrict__ wp, const float* __restrict__ wk,
                            const float* __restrict__ wv, ushort_t* __restrict__ ub) {
    __shared__ float tile[64][65];
    const int b = blockIdx.x, t = threadIdx.x;
    const float* src; ushort_t* dst; int dstld, k0, d0;
    if (b < 64)      { src = wp; dst = ub + U_WPT; dstld = 1024; k0 = (b >> 2) * 64; d0 = (b & 3) * 64; }
    else if (b < 80) { int c = b - 64; src = wk; dst = ub + U_WKT; dstld = 256; k0 = (c >> 2) * 64; d0 = (c & 3) * 64; }
    else             { int c = b - 80; src = wv; dst = ub + U_WVT; dstld = 256; k0 = (c >> 2) * 64; d0 = (c & 3) * 64; }
    for (int i = 0; i < 16; ++i) {
        int f = t + i * 256; int r = f >> 6, c = f & 63;
        tile[c][r] = src[(size_t)(k0 + r) * 256 + d0 + c];
    }
    __syncthreads();
    for (int i = 0; i < 16; ++i) {
        int o = t + i * 256; int dr = o >> 6, dc = o & 63;
        dst[(size_t)(d0 + dr) * dstld + k0 + dc] = f2bf(tile[dr][dc]);
    }
}

struct PrepArgs {
    const float* xo[6];
    const float* w1[6];
    int sz[6];
};

// ---------------- per-pathway SNN ----------------
__global__ void snn_kernel(PrepArgs pa, const float* __restrict__ sb1,
                           const float* __restrict__ sw2, const float* __restrict__ sb2,
                           float* __restrict__ bag) {
    __shared__ float xsh[600];
    __shared__ float t1sh[256];
    const int i = blockIdx.x;
    const int t = threadIdx.x;
    const int s = pa.sz[i];
    const float* xo = pa.xo[i];
    const float* w1 = pa.w1[i];
    for (int j = t; j < s; j += 256) xsh[j] = xo[j];
    __syncthreads();
    float acc = sb1[i * 256 + t];
    for (int j = 0; j < s; ++j) acc += xsh[j] * w1[j * 256 + t];
    t1sh[t] = acc > 0.f ? acc : expm1f(acc);
    __syncthreads();
    float acc2 = sb2[i * 256 + t];
    const float* w2 = sw2 + (size_t)i * 256 * 256;
    for (int j = 0; j < 256; ++j) acc2 += t1sh[j] * w2[j * 256 + t];
    bag[i * 256 + t] = acc2 > 0.f ? acc2 : expm1f(acc2);
}

// ---------------- gene scores, top-3 select, q projection ----------------
__global__ void select_kernel(const float* __restrict__ wa1, const float* __restrict__ ba1,
                              const float* __restrict__ wa2, const float* __restrict__ ba2,
                              const float* __restrict__ wq, const float* __restrict__ bq,
                              float* __restrict__ wsf) {
    __shared__ float bsh[6][256];
    __shared__ float ysh[64];
    __shared__ float ssh[8];
    __shared__ int isel[3];
    const int t = threadIdx.x;
    for (int j = t; j < 1536; j += 256) ((float*)bsh)[j] = wsf[WS_BAG + j];
    __syncthreads();
    for (int i = 0; i < 6; ++i) {
        if (t < 64) {
            float acc = ba1[t];
            for (int j = 0; j < 256; ++j) acc += bsh[i][j] * wa1[j * 64 + t];
            ysh[t] = fmaxf(acc, 0.f) * wa2[t];
        }
        __syncthreads();
        if (t == 0) {
            float sc = ba2[0];
            for (int j = 0; j < 64; ++j) sc += ysh[j];
            ssh[i] = sc;
        }
        __syncthreads();
    }
    if (t == 0) {
        float sc[6];
        for (int i = 0; i < 6; ++i) sc[i] = ssh[i];
        for (int k = 0; k < 3; ++k) {
            int best = 0; float bv = sc[0];
            for (int i = 1; i < 6; ++i) if (sc[i] > bv) { bv = sc[i]; best = i; }
            isel[k] = best;
            sc[best] = -INFINITY;
        }
    }
    __syncthreads();
    float g = 0.f;
    for (int k = 0; k < 3; ++k) {
        float v = bsh[isel[k]][t];
        wsf[WS_SEL + k * 256 + t] = v;
        g += v;
    }
    wsf[WS_GENE + t] = g * (1.f / 3.f);
    for (int k = 0; k < 3; ++k) {
        float acc = bq[t];
        const float* srow = bsh[isel[k]];
        for (int j = 0; j < 256; ++j) acc += srow[j] * wq[j * 256 + t];
        wsf[WS_QV + k * 256 + t] = acc * 0.17677669529663687f;
    }
}

// ---------------- fused main: MFMA wsi + k/v proj + flash attn partials + pooling ----------------
__global__ __launch_bounds__(256, 2) void main_kernel(
    const float* __restrict__ xp, const float* __restrict__ bp,
    const float* __restrict__ bk, const float* __restrict__ bv,
    const ushort_t* __restrict__ ub, float* __restrict__ wsf)
{
    __shared__ __align__(16) char xbuf[16384];          // x chunk bf16 [32][256] swizzled; pool scratch at end
    __shared__ __align__(16) ushort_t wsi_s[32 * 256];  // [p][d] swizzled (p&7)<<4
    __shared__ __align__(16) ushort_t k_s[32 * 256];    // [p][d] swizzled (p&7)<<4
    __shared__ __align__(16) ushort_t vT_s[256 * 32];   // [d][p] swizzled (d&14)<<2
    __shared__ __align__(16) float q_s[NHQ * 32];
    __shared__ __align__(16) ushort_t p_s[NHQ * 32];
    __shared__ float m_s[NHQ], l_s[NHQ], c_s[NHQ];

    const int tid = threadIdx.x;
    const int b = blockIdx.x;
    const int lane = tid & 63;
    const int w = tid >> 6;
    const int lm = lane & 15;
    const int lg = lane >> 4;
    const int wd0 = w * 64;

    const ushort_t* wpT = ub + U_WPT;
    const ushort_t* wkT = ub + U_WKT;
    const ushort_t* wvT = ub + U_WVT;

    for (int j = tid; j < 768; j += 256) {
        int kq = j >> 8, r = j & 255;
        q_s[((r >> 5) * 3 + kq) * 32 + (r & 31)] = wsf[WS_QV + j];
    }
    if (tid < NHQ) { m_s[tid] = -INFINITY; l_s[tid] = 0.f; c_s[tid] = 0.f; }

    float a_acc[3] = {0.f, 0.f, 0.f};
    f32x4 pl0 = {0.f,0.f,0.f,0.f}, pl1 = {0.f,0.f,0.f,0.f}, pl2 = {0.f,0.f,0.f,0.f};
    __syncthreads();

    for (int tt = b; tt < NTILES; tt += NB) {
        const int n0 = tt * TP;
        const int bin = (n0 >= 40000) ? 2 : (n0 >= 20000 ? 1 : 0);

        f32x4 acc[8];
#pragma unroll
        for (int i = 0; i < 8; ++i) acc[i] = (f32x4){0.f,0.f,0.f,0.f};

        // ---- phase 1: wsiT = wpT @ x^T over 4 K-chunks of 256 ----
        for (int ch = 0; ch < 4; ++ch) {
            float4 xr[8];
#pragma unroll
            for (int i = 0; i < 8; ++i) {
                int f4 = tid + i * 256;
                int p = f4 >> 6, c4 = f4 & 63;
                xr[i] = *(const float4*)(xp + (size_t)(n0 + p) * 1024 + ch * 256 + c4 * 4);
            }
            __syncthreads();
#pragma unroll
            for (int i = 0; i < 8; ++i) {
                int f4 = tid + i * 256;
                int p = f4 >> 6, c4 = f4 & 63;
                int byte = (p << 9) + (c4 << 3);
                byte ^= (p & 7) << 4;
                uint2 wv2; wv2.x = pk2(xr[i].x, xr[i].y); wv2.y = pk2(xr[i].z, xr[i].w);
                *(uint2*)(xbuf + byte) = wv2;
            }
            __syncthreads();
#pragma unroll
            for (int ks = 0; ks < 8; ++ks) {
                bf16x8 bfr[2];
#pragma unroll
                for (int pt = 0; pt < 2; ++pt) {
                    int p = pt * 16 + lm;
                    int byte = (p << 9) + ((ks * 32 + lg * 8) << 1);
                    byte ^= (p & 7) << 4;
                    bfr[pt] = *(const bf16x8*)(xbuf + byte);
                }
#pragma unroll
                for (int dt = 0; dt < 4; ++dt) {
                    bf16x8 af = *(const bf16x8*)(wpT + (size_t)(wd0 + dt * 16 + lm) * 1024 + ch * 256 + ks * 32 + lg * 8);
                    acc[dt * 2 + 0] = __builtin_amdgcn_mfma_f32_16x16x32_bf16(af, bfr[0], acc[dt * 2 + 0], 0, 0, 0);
                    acc[dt * 2 + 1] = __builtin_amdgcn_mfma_f32_16x16x32_bf16(af, bfr[1], acc[dt * 2 + 1], 0, 0, 0);
                }
            }
        }
        // phase-1 epilogue: relu(acc + bp) -> wsi_s[p][d] bf16 (packed b64)
#pragma unroll
        for (int dt = 0; dt < 4; ++dt) {
            int d0 = wd0 + dt * 16 + lg * 4;
            float4 bb = *(const float4*)(bp + d0);
#pragma unroll
            for (int pt = 0; pt < 2; ++pt) {
                int p = pt * 16 + lm;
                f32x4 v = acc[dt * 2 + pt];
                float r0 = fmaxf(v[0] + bb.x, 0.f);
                float r1 = fmaxf(v[1] + bb.y, 0.f);
                float r2 = fmaxf(v[2] + bb.z, 0.f);
                float r3 = fmaxf(v[3] + bb.w, 0.f);
                int byte = (p << 9) + (d0 << 1);
                byte ^= (p & 7) << 4;
                uint2 wv2; wv2.x = pk2(r0, r1); wv2.y = pk2(r2, r3);
                *(uint2*)((char*)wsi_s + byte) = wv2;
            }
        }
        __syncthreads();

        // ---- pooling partials (reads wsi_s) ----
        {
            int d4 = (tid & 63) * 4;
            int pg = tid >> 6;
            f32x4 sum = {0.f,0.f,0.f,0.f};
#pragma unroll
            for (int pp = 0; pp < 8; ++pp) {
                int p = pg * 8 + pp;
                int byte = (p << 9) + (d4 << 1);
                byte ^= (p & 7) << 4;
                uint2 u = *(const uint2*)((const char*)wsi_s + byte);
                sum[0] += bf2f(u.x & 0xffffu);
                sum[1] += bf2f(u.x >> 16);
                sum[2] += bf2f(u.y & 0xffffu);
                sum[3] += bf2f(u.y >> 16);
            }
            if (bin == 0) pl0 += sum; else if (bin == 1) pl1 += sum; else pl2 += sum;
        }

        // ---- phase 2: kT = wkT @ wsi^T ; vT = wvT @ wsi^T ----
#pragma unroll
        for (int mat = 0; mat < 2; ++mat) {
            const ushort_t* wt = mat ? wvT : wkT;
#pragma unroll
            for (int i = 0; i < 8; ++i) acc[i] = (f32x4){0.f,0.f,0.f,0.f};
#pragma unroll
            for (int ks = 0; ks < 8; ++ks) {
                bf16x8 bfr[2];
#pragma unroll
                for (int pt = 0; pt < 2; ++pt) {
                    int p = pt * 16 + lm;
                    int byte = (p << 9) + ((ks * 32 + lg * 8) << 1);
                    byte ^= (p & 7) << 4;
                    bfr[pt] = *(const bf16x8*)((const char*)wsi_s + byte);
                }
#pragma unroll
                for (int dt = 0; dt < 4; ++dt) {
                    bf16x8 af = *(const bf16x8*)(wt + (size_t)(wd0 + dt * 16 + lm) * 256 + ks * 32 + lg * 8);
                    acc[dt * 2 + 0] = __builtin_amdgcn_mfma_f32_16x16x32_bf16(af, bfr[0], acc[dt * 2 + 0], 0, 0, 0);
                    acc[dt * 2 + 1] = __builtin_amdgcn_mfma_f32_16x16x32_bf16(af, bfr[1], acc[dt * 2 + 1], 0, 0, 0);
                }
            }
            const float* bias = mat ? bv : bk;
#pragma unroll
            for (int dt = 0; dt < 4; ++dt) {
                int d0 = wd0 + dt * 16 + lg * 4;
                float4 bb = *(const float4*)(bias + d0);
#pragma unroll
                for (int pt = 0; pt < 2; ++pt) {
                    int p = pt * 16 + lm;
                    f32x4 v = acc[dt * 2 + pt];
                    float r0 = v[0] + bb.x;
                    float r1 = v[1] + bb.y;
                    float r2 = v[2] + bb.z;
                    float r3 = v[3] + bb.w;
                    if (mat == 0) {
                        int byte = (p << 9) + (d0 << 1);
                        byte ^= (p & 7) << 4;
                        uint2 wv2; wv2.x = pk2(r0, r1); wv2.y = pk2(r2, r3);
                        *(uint2*)((char*)k_s + byte) = wv2;
                    } else {
                        float rr[4] = {r0, r1, r2, r3};
#pragma unroll
                        for (int j = 0; j < 4; ++j) {
                            int d = d0 + j;
                            int byte = (d << 6) + (p << 1);
                            byte ^= (d & 14) << 2;
                            *(ushort_t*)((char*)vT_s + byte) = f2bf(rr[j]);
                        }
                    }
                }
            }
        }
        __syncthreads();

        // ---- phase 3: scores + online softmax (wave-parallel) ----
        float sv[3];
#pragma unroll
        for (int j = 0; j < 3; ++j) {
            int e = tid + j * 256;
            int hq = e >> 5, p = e & 31, h = hq / 3;
            float s = 0.f;
#pragma unroll
            for (int seg = 0; seg < 4; ++seg) {
                int byte = (p << 9) + ((h * 32 + seg * 8) << 1);
                byte ^= (p & 7) << 4;
                uint4 kk = *(const uint4*)((const char*)k_s + byte);
                const float* qp = &q_s[hq * 32 + seg * 8];
                float4 qa = *(const float4*)qp;
                float4 qb = *(const float4*)(qp + 4);
                s += qa.x * bf2f(kk.x & 0xffffu) + qa.y * bf2f(kk.x >> 16)
                   + qa.z * bf2f(kk.y & 0xffffu) + qa.w * bf2f(kk.y >> 16)
                   + qb.x * bf2f(kk.z & 0xffffu) + qb.y * bf2f(kk.z >> 16)
                   + qb.z * bf2f(kk.w & 0xffffu) + qb.w * bf2f(kk.w >> 16);
            }
            sv[j] = s;
        }
#pragma unroll
        for (int j = 0; j < 3; ++j) {
            int e = tid + j * 256;
            int hq = e >> 5, p = e & 31;
            float tmax = sv[j];
#pragma unroll
            for (int off = 16; off >= 1; off >>= 1) tmax = fmaxf(tmax, __shfl_xor(tmax, off));
            float m_old = m_s[hq];
            float mnew = fmaxf(m_old, tmax);
            float pe = __expf(sv[j] - mnew);
            float lsum = pe;
#pragma unroll
            for (int off = 16; off >= 1; off >>= 1) lsum += __shfl_xor(lsum, off);
            p_s[hq * 32 + p] = f2bf(pe);
            if (p == 0) {
                float corr = __expf(m_old - mnew);
                m_s[hq] = mnew;
                l_s[hq] = l_s[hq] * corr + lsum;
                c_s[hq] = corr;
            }
        }
        __syncthreads();

        // ---- phase 4: PV accumulate ----
#pragma unroll
        for (int j = 0; j < 3; ++j) {
            int e = tid + j * 256;
            int hq = e >> 5, dd = e & 31, h = hq / 3;
            float a = a_acc[j] * c_s[hq];
            int row = h * 32 + dd;
#pragma unroll
            for (int p8 = 0; p8 < 8; ++p8) {
                uint2 pv = *(const uint2*)(p_s + hq * 32 + p8 * 4);
                int byte = (row << 6) + (p8 << 3);
                byte ^= (row & 14) << 2;
                uint2 vv = *(const uint2*)((const char*)vT_s + byte);
                a += bf2f(pv.x & 0xffffu) * bf2f(vv.x & 0xffffu);
                a += bf2f(pv.x >> 16)     * bf2f(vv.x >> 16);
                a += bf2f(pv.y & 0xffffu) * bf2f(vv.y & 0xffffu);
                a += bf2f(pv.y >> 16)     * bf2f(vv.y >> 16);
            }
            a_acc[j] = a;
        }
        // next iteration's first __syncthreads protects LDS reuse
    }

    // ---- pooling cross-wave reduce via xbuf scratch ----
    float* scr = (float*)xbuf;
    {
        int d4 = (tid & 63) * 4;
        int pg = tid >> 6;
        *(f32x4*)(scr + (pg * 3 + 0) * 256 + d4) = pl0;
        *(f32x4*)(scr + (pg * 3 + 1) * 256 + d4) = pl1;
        *(f32x4*)(scr + (pg * 3 + 2) * 256 + d4) = pl2;
    }
    __syncthreads();
#pragma unroll
    for (int bin = 0; bin < 3; ++bin) {
        float s = scr[(0 * 3 + bin) * 256 + tid] + scr[(1 * 3 + bin) * 256 + tid]
                + scr[(2 * 3 + bin) * 256 + tid] + scr[(3 * 3 + bin) * 256 + tid];
        wsf[WS_PPOOL + b * 768 + bin * 256 + tid] = s;
    }
    if (tid < NHQ) {
        wsf[WS_PM + b * NHQ + tid] = m_s[tid];
        wsf[WS_PL + b * NHQ + tid] = l_s[tid];
    }
#pragma unroll
    for (int j = 0; j < 3; ++j)
        wsf[WS_PACC + b * 768 + tid + j * 256] = a_acc[j];
}

// ---------------- combine partials ----------------
__global__ void combine_kernel(float* __restrict__ wsf) {
    const int bidx = blockIdx.x;
    const int t = threadIdx.x;
    if (bidx < NHQ) {
        const int hq = bidx;
        float lm = -INFINITY;
        for (int b = t; b < NB; b += 64) lm = fmaxf(lm, wsf[WS_PM + b * NHQ + hq]);
#pragma unroll
        for (int o = 32; o > 0; o >>= 1) lm = fmaxf(lm, __shfl_xor(lm, o));
        const float M = lm;
        float L = 0.f;
        for (int b = t; b < NB; b += 64)
            L += wsf[WS_PL + b * NHQ + hq] * __expf(wsf[WS_PM + b * NHQ + hq] - M);
#pragma unroll
        for (int o = 32; o > 0; o >>= 1) L += __shfl_xor(L, o);
        const int dd = t & 31, half = t >> 5;
        float O = 0.f;
        for (int b = half; b < NB; b += 2)
            O += wsf[WS_PACC + b * 768 + hq * 32 + dd] * __expf(wsf[WS_PM + b * NHQ + hq] - M);
        O += __shfl_xor(O, 32);
        if (t < 32) {
            int h = hq / 3, kq = hq - h * 3;
            wsf[WS_ATTN + kq * 256 + h * 32 + dd] = O / L;
        }
    } else {
        const int bin = bidx - NHQ;
        for (int rep = 0; rep < 4; ++rep) {
            int d = rep * 64 + t;
            float s = 0.f;
            for (int b = 0; b < NB; ++b) s += wsf[WS_PPOOL + b * 768 + bin * 256 + d];
            wsf[WS_POOLED + bin * 256 + d] = s * (1.f / 20000.f);
        }
    }
}

// ---------------- epilogue ----------------
__device__ __forceinline__ float block_sum256(float v, float* red, int t) {
#pragma unroll
    for (int o = 32; o > 0; o >>= 1) v += __shfl_xor(v, o);
    if ((t & 63) == 0) red[t >> 6] = v;
    __syncthreads();
    float r = red[0] + red[1] + red[2] + red[3];
    __syncthreads();
    return r;
}

__global__ void final_kernel(const float* __restrict__ wo, const float* __restrict__ bo,
                             const float* __restrict__ ln1g, const float* __restrict__ ln1b,
                             const float* __restrict__ wf1, const float* __restrict__ bf1,
                             const float* __restrict__ wf2, const float* __restrict__ bf2,
                             const float* __restrict__ ln2g, const float* __restrict__ ln2b,
                             const float* __restrict__ wc, const float* __restrict__ bc,
                             float* __restrict__ wsf, float* __restrict__ out) {
    __shared__ float attnC[3][256];
    __shared__ float att[3][256];
    __shared__ float amean[256];
    __shared__ float gf[256];
    __shared__ float f1[256];
    __shared__ float red[256];
    const int t = threadIdx.x;
    for (int j = t; j < 768; j += 256) ((float*)attnC)[j] = wsf[WS_ATTN + j];
    gf[t] = wsf[WS_GENE + t];
    __syncthreads();
    for (int kq = 0; kq < 3; ++kq) {
        float acc = bo[t];
        for (int j = 0; j < 256; ++j) acc += attnC[kq][j] * wo[j * 256 + t];
        float x = acc + wsf[WS_POOLED + kq * 256 + t];
        float m = block_sum256(x, red, t) * (1.f / 256.f);
        float dv = x - m;
        float var = block_sum256(dv * dv, red, t) * (1.f / 256.f);
        att[kq][t] = dv * rsqrtf(var + LN_EPS) * ln1g[t] + ln1b[t];
    }
    __syncthreads();
    amean[t] = (att[0][t] + att[1][t] + att[2][t]) * (1.f / 3.f);
    __syncthreads();
    {
        float acc = bf1[t];
        for (int j = 0; j < 256; ++j) acc += amean[j] * wf1[j * 256 + t];
        for (int j = 0; j < 256; ++j) acc += gf[j] * wf1[(256 + j) * 256 + t];
        f1[t] = fmaxf(acc, 0.f);
    }
    __syncthreads();
    float acc2 = bf2[t];
    for (int j = 0; j < 256; ++j) acc2 += f1[j] * wf2[j * 256 + t];
    float y = fmaxf(acc2, 0.f) + amean[t];
    float m2 = block_sum256(y, red, t) * (1.f / 256.f);
    float dv2 = y - m2;
    float v2 = block_sum256(dv2 * dv2, red, t) * (1.f / 256.f);
    float fused = dv2 * rsqrtf(v2 + LN_EPS) * ln2g[t] + ln2b[t];
    red[t] = fused;
    __syncthreads();
    if (t < 4) {
        float o = bc[t];
        for (int j = 0; j < 256; ++j) o += red[j] * wc[j * 4 + t];
        out[t] = o;
    }
}

// ---------------- launcher ----------------
extern "C" void kernel_launch(void* const* d_in, const int* in_sizes, int n_in,
                              void* d_out, int out_size, void* d_ws, size_t ws_size,
                              hipStream_t stream) {
    const float* xp = (const float*)d_in[0];
    PrepArgs pa;
    for (int i = 0; i < 6; ++i) {
        pa.xo[i] = (const float*)d_in[1 + i];
        pa.w1[i] = (const float*)d_in[7 + i];
        pa.sz[i] = in_sizes[1 + i];
    }
    const float* sb1 = (const float*)d_in[13];
    const float* sw2 = (const float*)d_in[14];
    const float* sb2 = (const float*)d_in[15];
    const float* wp  = (const float*)d_in[16];
    const float* bp  = (const float*)d_in[17];
    const float* wa1 = (const float*)d_in[18];
    const float* ba1 = (const float*)d_in[19];
    const float* wa2 = (const float*)d_in[20];
    const float* ba2 = (const float*)d_in[21];
    const float* wq  = (const float*)d_in[22];
    const float* wk  = (const float*)d_in[23];
    const float* wv  = (const float*)d_in[24];
    const float* wo  = (const float*)d_in[25];
    const float* bq  = (const float*)d_in[26];
    const float* bk  = (const float*)d_in[27];
    const float* bv  = (const float*)d_in[28];
    const float* bo  = (const float*)d_in[29];
    const float* ln1g = (const float*)d_in[30];
    const float* ln1b = (const float*)d_in[31];
    const float* wf1 = (const float*)d_in[32];
    const float* bf1 = (const float*)d_in[33];
    const float* wf2 = (const float*)d_in[34];
    const float* bf2 = (const float*)d_in[35];
    const float* ln2g = (const float*)d_in[36];
    const float* ln2b = (const float*)d_in[37];
    const float* wc  = (const float*)d_in[38];
    const float* bc  = (const float*)d_in[39];

    float* wsf = (float*)d_ws;
    float* out = (float*)d_out;
    ushort_t* ub = (ushort_t*)(wsf + WS_BF16);

    prep_kernel<<<dim3(96), dim3(256), 0, stream>>>(wp, wk, wv, ub);
    snn_kernel<<<dim3(6), dim3(256), 0, stream>>>(pa, sb1, sw2, sb2, wsf + WS_BAG);
    select_kernel<<<dim3(1), dim3(256), 0, stream>>>(wa1, ba1, wa2, ba2, wq, bq, wsf);
    main_kernel<<<dim3(NB), dim3(256), 0, stream>>>(xp, bp, bk, bv, ub, wsf);
    combine_kernel<<<dim3(27), dim3(64), 0, stream>>>(wsf);
    final_kernel<<<dim3(1), dim3(256), 0, stream>>>(wo, bo, ln1g, ln1b, wf1, bf1, wf2, bf2,
                                                    ln2g, ln2b, wc, bc, wsf, out);
}

// Round 3
// 740.630 us; speedup vs baseline: 1.8462x; 1.6525x over previous
//
#include <hip/hip_runtime.h>
#include <hip/hip_bf16.h>
#include <math.h>

typedef unsigned short ushort_t;
typedef __attribute__((ext_vector_type(8))) short bf16x8;
typedef __attribute__((ext_vector_type(4))) float f32x4;

// ---------------- problem constants ----------------
#define NB 512             // workspace stride sizing (max blocks)
#define NBLK 469           // actual blocks: ceil(60000/128)
#define TP 128             // patches per tile
#define NHQ 24             // 8 heads * 3 queries
#define LN_EPS 1e-5f

// ---------------- workspace layout (float offsets) ----------------
#define WS_BAG 0                        // 6*256
#define WS_SEL 1536                     // 3*256
#define WS_GENE 2304                    // 256
#define WS_PM 3584                      // NB*24
#define WS_PL (WS_PM + NB*NHQ)
#define WS_PACC (WS_PL + NB*NHQ)        // NB*768
#define WS_PPOOL (WS_PACC + NB*768)     // NB*768
#define WS_ATTN (WS_PPOOL + NB*768)     // 768
#define WS_POOLED (WS_ATTN + 768)       // 768
#define WS_BF16 (WS_POOLED + 768)       // bf16 region start (16B aligned)
// ushort offsets inside bf16 region (fragment-packed weights)
#define U_WPT 0                         // 16 D16-blocks * 32 K32-blocks * 512
#define U_WKT 262144                    // 16 * 8 * 512
#define U_WVT 327680                    // 16 * 8 * 512
#define U_QB  393216                    // 24*32 bf16 q (pre-scaled)

// ---------------- helpers ----------------
__device__ __forceinline__ ushort_t f2bf(float f) {
    __hip_bfloat16 h = __float2bfloat16(f);
    return *reinterpret_cast<ushort_t*>(&h);
}
__device__ __forceinline__ float bf2f(unsigned int u) {
    union { unsigned int i; float f; } c; c.i = u << 16; return c.f;
}
__device__ __forceinline__ unsigned int pk2(float a, float b) {
    return (unsigned int)f2bf(a) | ((unsigned int)f2bf(b) << 16);
}

// ---------------- prep: weights -> bf16 fragment-packed ----------------
// packed block (1024B): for lg 0..3, lm 0..15, e 0..7: W[K32*32+lg*8+e][D16*16+lm]
__global__ void prep_kernel(const float* __restrict__ wp, const float* __restrict__ wk,
                            const float* __restrict__ wv, ushort_t* __restrict__ ub) {
    const int b = blockIdx.x, t = threadIdx.x;
    if (b < 16) {
        const int D16 = b;
        for (int i = 0; i < 64; ++i) {
            int f = t + i * 256;
            int K32 = f >> 9, r = f & 511;
            int lg = r >> 7, lm2 = (r >> 3) & 15, e = r & 7;
            int k = K32 * 32 + lg * 8 + e, d = D16 * 16 + lm2;
            ub[U_WPT + D16 * 16384 + f] = f2bf(wp[(size_t)k * 256 + d]);
        }
    } else if (b < 32) {
        const int D16 = b - 16;
        for (int i = 0; i < 16; ++i) {
            int f = t + i * 256;
            int K32 = f >> 9, r = f & 511;
            int lg = r >> 7, lm2 = (r >> 3) & 15, e = r & 7;
            int k = K32 * 32 + lg * 8 + e, d = D16 * 16 + lm2;
            ub[U_WKT + D16 * 4096 + f] = f2bf(wk[(size_t)k * 256 + d]);
        }
    } else {
        const int D16 = b - 32;
        for (int i = 0; i < 16; ++i) {
            int f = t + i * 256;
            int K32 = f >> 9, r = f & 511;
            int lg = r >> 7, lm2 = (r >> 3) & 15, e = r & 7;
            int k = K32 * 32 + lg * 8 + e, d = D16 * 16 + lm2;
            ub[U_WVT + D16 * 4096 + f] = f2bf(wv[(size_t)k * 256 + d]);
        }
    }
}

struct PrepArgs {
    const float* xo[6];
    const float* w1[6];
    int sz[6];
};

// ---------------- per-pathway SNN ----------------
__global__ void snn_kernel(PrepArgs pa, const float* __restrict__ sb1,
                           const float* __restrict__ sw2, const float* __restrict__ sb2,
                           float* __restrict__ bag) {
    __shared__ float xsh[600];
    __shared__ float t1sh[256];
    const int i = blockIdx.x;
    const int t = threadIdx.x;
    const int s = pa.sz[i];
    const float* xo = pa.xo[i];
    const float* w1 = pa.w1[i];
    for (int j = t; j < s; j += 256) xsh[j] = xo[j];
    __syncthreads();
    float acc = sb1[i * 256 + t];
    for (int j = 0; j < s; ++j) acc += xsh[j] * w1[j * 256 + t];
    t1sh[t] = acc > 0.f ? acc : expm1f(acc);
    __syncthreads();
    float acc2 = sb2[i * 256 + t];
    const float* w2 = sw2 + (size_t)i * 256 * 256;
    for (int j = 0; j < 256; ++j) acc2 += t1sh[j] * w2[j * 256 + t];
    bag[i * 256 + t] = acc2 > 0.f ? acc2 : expm1f(acc2);
}

// ---------------- gene scores, top-3 select, q projection (-> bf16) ----------------
__global__ void select_kernel(const float* __restrict__ wa1, const float* __restrict__ ba1,
                              const float* __restrict__ wa2, const float* __restrict__ ba2,
                              const float* __restrict__ wq, const float* __restrict__ bq,
                              float* __restrict__ wsf, ushort_t* __restrict__ ub) {
    __shared__ float bsh[6][256];
    __shared__ float ysh[64];
    __shared__ float ssh[8];
    __shared__ int isel[3];
    const int t = threadIdx.x;
    for (int j = t; j < 1536; j += 256) ((float*)bsh)[j] = wsf[WS_BAG + j];
    __syncthreads();
    for (int i = 0; i < 6; ++i) {
        if (t < 64) {
            float acc = ba1[t];
            for (int j = 0; j < 256; ++j) acc += bsh[i][j] * wa1[j * 64 + t];
            ysh[t] = fmaxf(acc, 0.f) * wa2[t];
        }
        __syncthreads();
        if (t == 0) {
            float sc = ba2[0];
            for (int j = 0; j < 64; ++j) sc += ysh[j];
            ssh[i] = sc;
        }
        __syncthreads();
    }
    if (t == 0) {
        float sc[6];
        for (int i = 0; i < 6; ++i) sc[i] = ssh[i];
        for (int k = 0; k < 3; ++k) {
            int best = 0; float bv = sc[0];
            for (int i = 1; i < 6; ++i) if (sc[i] > bv) { bv = sc[i]; best = i; }
            isel[k] = best;
            sc[best] = -INFINITY;
        }
    }
    __syncthreads();
    float g = 0.f;
    for (int k = 0; k < 3; ++k) {
        float v = bsh[isel[k]][t];
        wsf[WS_SEL + k * 256 + t] = v;
        g += v;
    }
    wsf[WS_GENE + t] = g * (1.f / 3.f);
    // q = (selected @ wq + bq) * rsqrt(32) -> bf16, layout [hq][32]
    for (int kq = 0; kq < 3; ++kq) {
        float acc = bq[t];
        const float* srow = bsh[isel[kq]];
        for (int j = 0; j < 256; ++j) acc += srow[j] * wq[j * 256 + t];
        float v = acc * 0.17677669529663687f;
        int hq = (t >> 5) * 3 + kq, dd = t & 31;
        ub[U_QB + hq * 32 + dd] = f2bf(v);
    }
}

// ---------------- fused main ----------------
#define LOAD_X(xr, c) { \
    _Pragma("unroll") for (int i_ = 0; i_ < 4; ++i_) { \
        int f_ = tid + i_ * 512; int p_ = f_ >> 4, c4_ = f_ & 15; \
        if (n0 + p_ < 60000) \
            xr[i_] = *(const float4*)(xp + (size_t)(n0 + p_) * 1024 + (c) * 64 + c4_ * 4); \
        else { xr[i_].x = 0.f; xr[i_].y = 0.f; xr[i_].z = 0.f; xr[i_].w = 0.f; } } }

#define STORE_X(xr) { \
    _Pragma("unroll") for (int i_ = 0; i_ < 4; ++i_) { \
        int f_ = tid + i_ * 512; int p_ = f_ >> 4, c4_ = f_ & 15; \
        int byte_ = (p_ * 128 + c4_ * 8) ^ ((p_ & 7) << 4); \
        uint2 u_; u_.x = pk2(xr[i_].x, xr[i_].y); u_.y = pk2(xr[i_].z, xr[i_].w); \
        *(uint2*)((char*)x_s + byte_) = u_; } }

#define LOAD_W1(dst, c) { \
    _Pragma("unroll") for (int ks_ = 0; ks_ < 2; ++ks_) \
    _Pragma("unroll") for (int dt_ = 0; dt_ < 4; ++dt_) \
        dst[ks_ * 4 + dt_] = *(const bf16x8*)(wpP + ((size_t)(((w & 3) * 4 + dt_) * 32 + (c) * 2 + ks_)) * 512 + lane * 8); }

#define MFMA_CHUNK(wf) { \
    _Pragma("unroll") for (int ks_ = 0; ks_ < 2; ++ks_) { \
        bf16x8 bfr_[4]; \
        _Pragma("unroll") for (int pt_ = 0; pt_ < 4; ++pt_) { \
            int p_ = wp0 + pt_ * 16 + lm; \
            int byte_ = (p_ * 128 + ks_ * 64 + lg * 16) ^ ((p_ & 7) << 4); \
            bfr_[pt_] = *(const bf16x8*)((const char*)x_s + byte_); } \
        _Pragma("unroll") for (int dt_ = 0; dt_ < 4; ++dt_) \
        _Pragma("unroll") for (int pt_ = 0; pt_ < 4; ++pt_) \
            acc[dt_ * 4 + pt_] = __builtin_amdgcn_mfma_f32_16x16x32_bf16(wf[ks_ * 4 + dt_], bfr_[pt_], acc[dt_ * 4 + pt_], 0, 0, 0); } }

__global__ __launch_bounds__(512, 2) void main_kernel(
    const float* __restrict__ xp, const float* __restrict__ bp,
    const float* __restrict__ bk, const float* __restrict__ bv,
    const ushort_t* __restrict__ ub, float* __restrict__ wsf)
{
    __shared__ __align__(16) ushort_t wsi_s[128 * 256];  // [p][d], swz ^((p&7)<<4) on byte
    __shared__ __align__(16) ushort_t kv_s[128 * 256];   // k: [p][d] swz p; later vT: [d][p] swz d
    __shared__ __align__(16) ushort_t x_s[128 * 64];     // x chunk bf16 [p][64k] swz p; reused as f32 pool scratch
    __shared__ __align__(16) ushort_t p_s[NHQ * 128];    // P bf16 [hq][p]
    __shared__ float mlc_s[72];                          // m[24], l[24], c[24]

    const int tid = threadIdx.x;
    const int b = blockIdx.x;
    const int lane = tid & 63;
    const int w = tid >> 6;          // wave 0..7
    const int lm = lane & 15;
    const int lg = lane >> 4;
    const int lmc = (lm < 3) ? lm : 2;
    const int wd0 = (w & 3) * 64;    // d range of this wave
    const int wp0 = (w >> 2) * 64;   // p range of this wave

    const ushort_t* wpP = ub + U_WPT;
    const ushort_t* wkP = ub + U_WKT;
    const ushort_t* wvP = ub + U_WVT;

    // q fragment (B-operand for scores): lane lm = query row (3 valid), k-contig 8 dims
    bf16x8 qfrag;
    if (lm < 3) qfrag = *(const bf16x8*)(ub + U_QB + (w * 3 + lm) * 32 + lg * 8);
    else { bf16x8 z = {0,0,0,0,0,0,0,0}; qfrag = z; }

    if (tid < 24) { mlc_s[tid] = -INFINITY; mlc_s[24 + tid] = 0.f; mlc_s[48 + tid] = 0.f; }

    f32x4 pv[2] = {{0.f,0.f,0.f,0.f},{0.f,0.f,0.f,0.f}};
    float pl0 = 0.f, pl1 = 0.f, pl2 = 0.f;
    __syncthreads();

    const int n0 = b * TP;
    {
        // ================= phase 1: wsi = relu(x @ wp + bp) =================
        f32x4 acc[16];
#pragma unroll
        for (int i = 0; i < 16; ++i) acc[i] = (f32x4){0.f,0.f,0.f,0.f};

        float4 xr[4];
        bf16x8 wA[8], wB[8];
        LOAD_X(xr, 0); LOAD_W1(wA, 0);
        for (int c = 0; c < 16; c += 2) {
            __syncthreads();
            STORE_X(xr);
            __syncthreads();
            LOAD_X(xr, c + 1); LOAD_W1(wB, c + 1);
            MFMA_CHUNK(wA);
            __syncthreads();
            STORE_X(xr);
            __syncthreads();
            if (c + 2 < 16) { LOAD_X(xr, c + 2); LOAD_W1(wA, c + 2); }
            MFMA_CHUNK(wB);
        }
        // epilogue: relu + bias -> wsi_s
#pragma unroll
        for (int dt = 0; dt < 4; ++dt) {
            int d0 = wd0 + dt * 16 + lg * 4;
            float4 bb = *(const float4*)(bp + d0);
#pragma unroll
            for (int pt = 0; pt < 4; ++pt) {
                int p = wp0 + pt * 16 + lm;
                f32x4 v = acc[dt * 4 + pt];
                uint2 u;
                u.x = pk2(fmaxf(v[0] + bb.x, 0.f), fmaxf(v[1] + bb.y, 0.f));
                u.y = pk2(fmaxf(v[2] + bb.z, 0.f), fmaxf(v[3] + bb.w, 0.f));
                int byte = (p * 512 + d0 * 2) ^ ((p & 7) << 4);
                *(uint2*)((char*)wsi_s + byte) = u;
            }
        }
    }
    __syncthreads();

    // ================= pooling partials =================
    {
        int d = tid & 255, half = tid >> 8;
#pragma unroll 16
        for (int pp = 0; pp < 64; ++pp) {
            int p = half * 64 + pp;
            int gp = n0 + p;
            int byte = (p * 512 + d * 2) ^ ((p & 7) << 4);
            float v = bf2f((unsigned int)*(const ushort_t*)((const char*)wsi_s + byte));
            pl0 += (gp < 20000) ? v : 0.f;
            pl1 += (gp >= 20000 && gp < 40000) ? v : 0.f;
            pl2 += (gp >= 40000 && gp < 60000) ? v : 0.f;
        }
    }

    // ================= phase 2a: k = wsi @ wk + bk =================
    {
        f32x4 acc2[16];
#pragma unroll
        for (int i = 0; i < 16; ++i) acc2[i] = (f32x4){0.f,0.f,0.f,0.f};
#pragma unroll
        for (int ks = 0; ks < 8; ++ks) {
            bf16x8 wf[4];
#pragma unroll
            for (int dt = 0; dt < 4; ++dt)
                wf[dt] = *(const bf16x8*)(wkP + ((size_t)(((w & 3) * 4 + dt) * 8 + ks)) * 512 + lane * 8);
            bf16x8 bfr[4];
#pragma unroll
            for (int pt = 0; pt < 4; ++pt) {
                int p = wp0 + pt * 16 + lm;
                int byte = (p * 512 + (ks * 32 + lg * 8) * 2) ^ ((p & 7) << 4);
                bfr[pt] = *(const bf16x8*)((const char*)wsi_s + byte);
            }
#pragma unroll
            for (int dt = 0; dt < 4; ++dt)
#pragma unroll
                for (int pt = 0; pt < 4; ++pt)
                    acc2[dt * 4 + pt] = __builtin_amdgcn_mfma_f32_16x16x32_bf16(wf[dt], bfr[pt], acc2[dt * 4 + pt], 0, 0, 0);
        }
#pragma unroll
        for (int dt = 0; dt < 4; ++dt) {
            int d0 = wd0 + dt * 16 + lg * 4;
            float4 bb = *(const float4*)(bk + d0);
#pragma unroll
            for (int pt = 0; pt < 4; ++pt) {
                int p = wp0 + pt * 16 + lm;
                f32x4 v = acc2[dt * 4 + pt];
                uint2 u;
                u.x = pk2(v[0] + bb.x, v[1] + bb.y);
                u.y = pk2(v[2] + bb.z, v[3] + bb.w);
                int byte = (p * 512 + d0 * 2) ^ ((p & 7) << 4);
                *(uint2*)((char*)kv_s + byte) = u;
            }
        }
    }
    __syncthreads();

    // ================= scores + online softmax (wave = head) =================
    {
        f32x4 sc[8];
#pragma unroll
        for (int blk = 0; blk < 8; ++blk) {
            sc[blk] = (f32x4){0.f,0.f,0.f,0.f};
            int p = blk * 16 + lm;
            int byte = (p * 512 + (w * 32 + lg * 8) * 2) ^ ((p & 7) << 4);
            bf16x8 kf = *(const bf16x8*)((const char*)kv_s + byte);
            sc[blk] = __builtin_amdgcn_mfma_f32_16x16x32_bf16(kf, qfrag, sc[blk], 0, 0, 0);
        }
        float m_old = mlc_s[w * 3 + lmc];
        float tmax = -INFINITY;
#pragma unroll
        for (int blk = 0; blk < 8; ++blk)
#pragma unroll
            for (int j = 0; j < 4; ++j) {
                int p = blk * 16 + lg * 4 + j;
                if (n0 + p >= 60000) sc[blk][j] = -INFINITY;
                tmax = fmaxf(tmax, sc[blk][j]);
            }
        tmax = fmaxf(tmax, __shfl_xor(tmax, 16));
        tmax = fmaxf(tmax, __shfl_xor(tmax, 32));
        float mnew = fmaxf(m_old, tmax);
        float lsum = 0.f;
#pragma unroll
        for (int blk = 0; blk < 8; ++blk)
#pragma unroll
            for (int j = 0; j < 4; ++j) {
                float e = __expf(sc[blk][j] - mnew);
                sc[blk][j] = e;
                lsum += e;
            }
        lsum += __shfl_xor(lsum, 16);
        lsum += __shfl_xor(lsum, 32);
        float corr = __expf(m_old - mnew);
        if (lane < 3) {
            mlc_s[w * 3 + lane] = mnew;
            mlc_s[24 + w * 3 + lane] = mlc_s[24 + w * 3 + lane] * corr + lsum;
            mlc_s[48 + w * 3 + lane] = corr;
        }
        if (lm < 3) {
#pragma unroll
            for (int blk = 0; blk < 8; ++blk) {
                int p0 = blk * 16 + lg * 4;
                *(unsigned int*)(p_s + (w * 3 + lm) * 128 + p0) = pk2(sc[blk][0], sc[blk][1]);
                *(unsigned int*)(p_s + (w * 3 + lm) * 128 + p0 + 2) = pk2(sc[blk][2], sc[blk][3]);
            }
        }
    }
    __syncthreads();

    // ================= phase 2b: v = wsi @ wv + bv (as vT[d][p]) =================
    {
        f32x4 acc2[16];
#pragma unroll
        for (int i = 0; i < 16; ++i) acc2[i] = (f32x4){0.f,0.f,0.f,0.f};
#pragma unroll
        for (int ks = 0; ks < 8; ++ks) {
            bf16x8 wf[4];
#pragma unroll
            for (int dt = 0; dt < 4; ++dt)
                wf[dt] = *(const bf16x8*)(wvP + ((size_t)(((w & 3) * 4 + dt) * 8 + ks)) * 512 + lane * 8);
            bf16x8 bfr[4];
#pragma unroll
            for (int pt = 0; pt < 4; ++pt) {
                int p = wp0 + pt * 16 + lm;
                int byte = (p * 512 + (ks * 32 + lg * 8) * 2) ^ ((p & 7) << 4);
                bfr[pt] = *(const bf16x8*)((const char*)wsi_s + byte);
            }
#pragma unroll
            for (int dt = 0; dt < 4; ++dt)
#pragma unroll
                for (int pt = 0; pt < 4; ++pt)
                    acc2[dt * 4 + pt] = __builtin_amdgcn_mfma_f32_16x16x32_bf16(wf[dt], bfr[pt], acc2[dt * 4 + pt], 0, 0, 0);
        }
#pragma unroll
        for (int dt = 0; dt < 4; ++dt) {
            int d0 = wd0 + dt * 16 + lg * 4;
            float4 bb = *(const float4*)(bv + d0);
#pragma unroll
            for (int pt = 0; pt < 4; ++pt) {
                int p = wp0 + pt * 16 + lm;
                f32x4 v = acc2[dt * 4 + pt];
                float r[4] = {v[0] + bb.x, v[1] + bb.y, v[2] + bb.z, v[3] + bb.w};
#pragma unroll
                for (int j = 0; j < 4; ++j) {
                    int dd = d0 + j;
                    int byte = (dd * 256 + p * 2) ^ ((dd & 7) << 4);
                    *(ushort_t*)((char*)kv_s + byte) = f2bf(r[j]);
                }
            }
        }
    }
    __syncthreads();

    // ================= PV accumulate (wave = head, MFMA) =================
    {
        float cj[4];
#pragma unroll
        for (int j = 0; j < 4; ++j) {
            int q = lg * 4 + j;
            cj[j] = mlc_s[48 + w * 3 + (q < 3 ? q : 2)];
        }
#pragma unroll
        for (int nb = 0; nb < 2; ++nb)
#pragma unroll
            for (int j = 0; j < 4; ++j) pv[nb][j] *= cj[j];
#pragma unroll
        for (int ks = 0; ks < 4; ++ks) {
            bf16x8 pa = *(const bf16x8*)(p_s + (w * 3 + lmc) * 128 + ks * 32 + lg * 8);
#pragma unroll
            for (int nb = 0; nb < 2; ++nb) {
                int row = w * 32 + nb * 16 + lm;
                int byte = (row * 256 + (ks * 32 + lg * 8) * 2) ^ ((row & 7) << 4);
                bf16x8 vb = *(const bf16x8*)((const char*)kv_s + byte);
                pv[nb] = __builtin_amdgcn_mfma_f32_16x16x32_bf16(pa, vb, pv[nb], 0, 0, 0);
            }
        }
    }

    // ================= write per-block partials =================
    __syncthreads();
    {
        float* scr = (float*)x_s;
        int d = tid & 255, half = tid >> 8;
        scr[half * 768 + 0 * 256 + d] = pl0;
        scr[half * 768 + 1 * 256 + d] = pl1;
        scr[half * 768 + 2 * 256 + d] = pl2;
    }
    __syncthreads();
    if (tid < 256) {
        float* scr = (float*)x_s;
#pragma unroll
        for (int bin = 0; bin < 3; ++bin)
            wsf[WS_PPOOL + b * 768 + bin * 256 + tid] = scr[bin * 256 + tid] + scr[768 + bin * 256 + tid];
    }
    if (tid < 24) {
        wsf[WS_PM + b * 24 + tid] = mlc_s[tid];
        wsf[WS_PL + b * 24 + tid] = mlc_s[24 + tid];
    }
    if (lg == 0) {
#pragma unroll
        for (int nb = 0; nb < 2; ++nb)
#pragma unroll
            for (int j = 0; j < 3; ++j) {
                int hq = w * 3 + j, dd = nb * 16 + lm;
                wsf[WS_PACC + b * 768 + hq * 32 + dd] = pv[nb][j];
            }
    }
}

// ---------------- combine partials ----------------
__global__ void combine_kernel(float* __restrict__ wsf) {
    const int bidx = blockIdx.x;
    const int t = threadIdx.x;
    if (bidx < NHQ) {
        const int hq = bidx;
        float lmx = -INFINITY;
        for (int b = t; b < NBLK; b += 64) lmx = fmaxf(lmx, wsf[WS_PM + b * 24 + hq]);
#pragma unroll
        for (int o = 32; o > 0; o >>= 1) lmx = fmaxf(lmx, __shfl_xor(lmx, o));
        const float M = lmx;
        float L = 0.f;
        for (int b = t; b < NBLK; b += 64)
            L += wsf[WS_PL + b * 24 + hq] * __expf(wsf[WS_PM + b * 24 + hq] - M);
#pragma unroll
        for (int o = 32; o > 0; o >>= 1) L += __shfl_xor(L, o);
        const int dd = t & 31, half = t >> 5;
        float O = 0.f;
        for (int b = half; b < NBLK; b += 2)
            O += wsf[WS_PACC + b * 768 + hq * 32 + dd] * __expf(wsf[WS_PM + b * 24 + hq] - M);
        O += __shfl_xor(O, 32);
        if (t < 32) {
            int h = hq / 3, kq = hq - h * 3;
            wsf[WS_ATTN + kq * 256 + h * 32 + dd] = O / L;
        }
    } else {
        const int bin = bidx - NHQ;
        for (int rep = 0; rep < 4; ++rep) {
            int d = rep * 64 + t;
            float s = 0.f;
            for (int b = 0; b < NBLK; ++b) s += wsf[WS_PPOOL + b * 768 + bin * 256 + d];
            wsf[WS_POOLED + bin * 256 + d] = s * (1.f / 20000.f);
        }
    }
}

// ---------------- epilogue ----------------
__device__ __forceinline__ float block_sum256(float v, float* red, int t) {
#pragma unroll
    for (int o = 32; o > 0; o >>= 1) v += __shfl_xor(v, o);
    if ((t & 63) == 0) red[t >> 6] = v;
    __syncthreads();
    float r = red[0] + red[1] + red[2] + red[3];
    __syncthreads();
    return r;
}

__global__ void final_kernel(const float* __restrict__ wo, const float* __restrict__ bo,
                             const float* __restrict__ ln1g, const float* __restrict__ ln1b,
                             const float* __restrict__ wf1, const float* __restrict__ bf1,
                             const float* __restrict__ wf2, const float* __restrict__ bf2,
                             const float* __restrict__ ln2g, const float* __restrict__ ln2b,
                             const float* __restrict__ wc, const float* __restrict__ bc,
                             float* __restrict__ wsf, float* __restrict__ out) {
    __shared__ float attnC[3][256];
    __shared__ float att[3][256];
    __shared__ float amean[256];
    __shared__ float gf[256];
    __shared__ float f1[256];
    __shared__ float red[256];
    const int t = threadIdx.x;
    for (int j = t; j < 768; j += 256) ((float*)attnC)[j] = wsf[WS_ATTN + j];
    gf[t] = wsf[WS_GENE + t];
    __syncthreads();
    for (int kq = 0; kq < 3; ++kq) {
        float acc = bo[t];
        for (int j = 0; j < 256; ++j) acc += attnC[kq][j] * wo[j * 256 + t];
        float x = acc + wsf[WS_POOLED + kq * 256 + t];
        float m = block_sum256(x, red, t) * (1.f / 256.f);
        float dv = x - m;
        float var = block_sum256(dv * dv, red, t) * (1.f / 256.f);
        att[kq][t] = dv * rsqrtf(var + LN_EPS) * ln1g[t] + ln1b[t];
    }
    __syncthreads();
    amean[t] = (att[0][t] + att[1][t] + att[2][t]) * (1.f / 3.f);
    __syncthreads();
    {
        float acc = bf1[t];
        for (int j = 0; j < 256; ++j) acc += amean[j] * wf1[j * 256 + t];
        for (int j = 0; j < 256; ++j) acc += gf[j] * wf1[(256 + j) * 256 + t];
        f1[t] = fmaxf(acc, 0.f);
    }
    __syncthreads();
    float acc2 = bf2[t];
    for (int j = 0; j < 256; ++j) acc2 += f1[j] * wf2[j * 256 + t];
    float y = fmaxf(acc2, 0.f) + amean[t];
    float m2 = block_sum256(y, red, t) * (1.f / 256.f);
    float dv2 = y - m2;
    float v2 = block_sum256(dv2 * dv2, red, t) * (1.f / 256.f);
    float fused = dv2 * rsqrtf(v2 + LN_EPS) * ln2g[t] + ln2b[t];
    red[t] = fused;
    __syncthreads();
    if (t < 4) {
        float o = bc[t];
        for (int j = 0; j < 256; ++j) o += red[j] * wc[j * 4 + t];
        out[t] = o;
    }
}

// ---------------- launcher ----------------
extern "C" void kernel_launch(void* const* d_in, const int* in_sizes, int n_in,
                              void* d_out, int out_size, void* d_ws, size_t ws_size,
                              hipStream_t stream) {
    const float* xp = (const float*)d_in[0];
    PrepArgs pa;
    for (int i = 0; i < 6; ++i) {
        pa.xo[i] = (const float*)d_in[1 + i];
        pa.w1[i] = (const float*)d_in[7 + i];
        pa.sz[i] = in_sizes[1 + i];
    }
    const float* sb1 = (const float*)d_in[13];
    const float* sw2 = (const float*)d_in[14];
    const float* sb2 = (const float*)d_in[15];
    const float* wp  = (const float*)d_in[16];
    const float* bp  = (const float*)d_in[17];
    const float* wa1 = (const float*)d_in[18];
    const float* ba1 = (const float*)d_in[19];
    const float* wa2 = (const float*)d_in[20];
    const float* ba2 = (const float*)d_in[21];
    const float* wq  = (const float*)d_in[22];
    const float* wk  = (const float*)d_in[23];
    const float* wv  = (const float*)d_in[24];
    const float* wo  = (const float*)d_in[25];
    const float* bq  = (const float*)d_in[26];
    const float* bk  = (const float*)d_in[27];
    const float* bv  = (const float*)d_in[28];
    const float* bo  = (const float*)d_in[29];
    const float* ln1g = (const float*)d_in[30];
    const float* ln1b = (const float*)d_in[31];
    const float* wf1 = (const float*)d_in[32];
    const float* bf1 = (const float*)d_in[33];
    const float* wf2 = (const float*)d_in[34];
    const float* bf2 = (const float*)d_in[35];
    const float* ln2g = (const float*)d_in[36];
    const float* ln2b = (const float*)d_in[37];
    const float* wc  = (const float*)d_in[38];
    const float* bc  = (const float*)d_in[39];

    float* wsf = (float*)d_ws;
    float* out = (float*)d_out;
    ushort_t* ub = (ushort_t*)(wsf + WS_BF16);

    prep_kernel<<<dim3(48), dim3(256), 0, stream>>>(wp, wk, wv, ub);
    snn_kernel<<<dim3(6), dim3(256), 0, stream>>>(pa, sb1, sw2, sb2, wsf + WS_BAG);
    select_kernel<<<dim3(1), dim3(256), 0, stream>>>(wa1, ba1, wa2, ba2, wq, bq, wsf, ub);
    main_kernel<<<dim3(NBLK), dim3(512), 0, stream>>>(xp, bp, bk, bv, ub, wsf);
    combine_kernel<<<dim3(27), dim3(64), 0, stream>>>(wsf);
    final_kernel<<<dim3(1), dim3(256), 0, stream>>>(wo, bo, ln1g, ln1b, wf1, bf1, wf2, bf2,
                                                    ln2g, ln2b, wc, bc, wsf, out);
}